// Round 2
// baseline (1081.964 us; speedup 1.0000x reference)
//
#include <hip/hip_runtime.h>
#include <math.h>

#define NN 100000
#define NE 1600000
#define CC 64
#define ECH 32
#define NB 3125          // dst buckets of 32 nodes; 32*3125 == 100000 exactly

// ---------------- Kernel 1: m = x @ W  ([N,64] @ [64,64]) ----------------
__global__ __launch_bounds__(256) void k_xW(const float* __restrict__ x,
                                            const float* __restrict__ W,
                                            float* __restrict__ m) {
    __shared__ float xs[64][64];
    __shared__ float ws[64][64];
    const int t = threadIdx.x;
    const int j = t & 63;
    const int g = t >> 6;
    const int base = blockIdx.x * 64;
#pragma unroll
    for (int r = 0; r < 16; ++r) {
        int idx = r * 256 + t;
        ws[idx >> 6][idx & 63] = W[idx];
    }
#pragma unroll
    for (int r = 0; r < 16; ++r) {
        int idx = r * 256 + t;
        int n = idx >> 6, k = idx & 63;
        int gi = base + n;
        xs[n][k] = (gi < NN) ? x[gi * 64 + k] : 0.f;
    }
    __syncthreads();
    float acc[16];
#pragma unroll
    for (int q = 0; q < 16; ++q) acc[q] = 0.f;
    for (int k = 0; k < 64; ++k) {
        float w = ws[k][j];
#pragma unroll
        for (int q = 0; q < 16; ++q)
            acc[q] = fmaf(xs[g * 16 + q][k], w, acc[q]);
    }
#pragma unroll
    for (int q = 0; q < 16; ++q) {
        int n = base + g * 16 + q;
        if (n < NN) m[n * 64 + j] = acc[q];
    }
}

// ---------------- Pass 1: histogram of dst buckets ----------------
__global__ __launch_bounds__(256) void k_hist(const int* __restrict__ ei,
                                              int* __restrict__ counts) {
    int i = blockIdx.x * 256 + threadIdx.x;
    int stride = gridDim.x * 256;
    for (int e = i; e < NE; e += stride)
        atomicAdd(&counts[ei[NE + e] >> 5], 1);
}

// ---------------- Pass 2: exclusive scan (single block) ----------------
__global__ __launch_bounds__(256) void k_scan(const int* __restrict__ counts,
                                              int* __restrict__ starts,
                                              int* __restrict__ cursor) {
    __shared__ int part[256];
    __shared__ int lds[NB];
    const int t = threadIdx.x;
    const int per = (NB + 255) / 256;   // 13
    int base = t * per;
    int s = 0;
    for (int i = 0; i < per; ++i) {
        int g = base + i;
        int v = (g < NB) ? counts[g] : 0;
        if (g < NB) lds[g] = v;
        s += v;
    }
    part[t] = s;
    __syncthreads();
    for (int off = 1; off < 256; off <<= 1) {
        int v = (t >= off) ? part[t - off] : 0;
        __syncthreads();
        part[t] += v;
        __syncthreads();
    }
    int excl = (t == 0) ? 0 : part[t - 1];
    for (int i = 0; i < per; ++i) {
        int g = base + i;
        if (g < NB) {
            int v = lds[g];
            starts[g] = excl;
            cursor[g] = excl;
            excl += v;
        }
    }
    if (t == 255) starts[NB] = part[255];   // == NE
}

// ---------------- Pass 3: scatter edge payloads into bucket order ----------
// payload: (e | dst_local<<24, src)   (e < 2^21, dst_local < 32)
__global__ __launch_bounds__(256) void k_scatter(const int* __restrict__ ei,
                                                 int* __restrict__ cursor,
                                                 int2* __restrict__ sorted) {
    int i = blockIdx.x * 256 + threadIdx.x;
    int stride = gridDim.x * 256;
    for (int e = i; e < NE; e += stride) {
        int s = ei[e];
        int d = ei[NE + e];
        int pos = atomicAdd(&cursor[d >> 5], 1);
        sorted[pos] = make_int2(e | ((d & 31) << 24), s);
    }
}

// ---------------- Pass 4: per-bucket LDS aggregation ----------------------
// Block = bucket of 32 dst nodes. acc[32][64] f32 in LDS. Wave-per-edge,
// 1-ahead pipeline: payload/ea/m loads for edge i+1 in flight while edge i
// computes its We·ea dot and ds_add_f32 accumulates.
__global__ __launch_bounds__(256) void k_agg(const int2* __restrict__ sorted,
                                             const int* __restrict__ starts,
                                             const float* __restrict__ ea,
                                             const float* __restrict__ We,
                                             const float* __restrict__ m,
                                             float* __restrict__ agg) {
    __shared__ float acc[32][64];
    const int t = threadIdx.x;
    const int lane = t & 63;
    const int wv = t >> 6;            // 0..3
    const int b = blockIdx.x;
#pragma unroll
    for (int r = 0; r < 8; ++r) {
        int i = r * 256 + t;
        acc[i >> 6][i & 63] = 0.f;
    }
    float4 w[8];
    const float4* wp = (const float4*)(We + lane * 32);
#pragma unroll
    for (int c = 0; c < 8; ++c) w[c] = wp[c];
    __syncthreads();

    int idx = starts[b] + wv;
    const int end = starts[b + 1];
    bool v0 = idx < end;
    int2 cur = make_int2(0, 0);
    float4 A[8];
    float mg = 0.f;
    if (v0) {
        cur = sorted[idx];
        const float4* p = (const float4*)(ea + (size_t)(cur.x & 0xFFFFFF) * 32);
#pragma unroll
        for (int c = 0; c < 8; ++c) A[c] = p[c];
        mg = m[(size_t)cur.y * 64 + lane];
    }
    while (v0) {
        int nidx = idx + 4;
        bool v1 = nidx < end;
        int2 nxt = make_int2(0, 0);
        float4 B[8];
        float mg2 = 0.f;
        if (v1) {
            nxt = sorted[nidx];
            const float4* p = (const float4*)(ea + (size_t)(nxt.x & 0xFFFFFF) * 32);
#pragma unroll
            for (int c = 0; c < 8; ++c) B[c] = p[c];
            mg2 = m[(size_t)nxt.y * 64 + lane];
        }
        // compute current edge
        float coef = 0.f;
#pragma unroll
        for (int c = 0; c < 8; ++c) {
            coef = fmaf(A[c].x, w[c].x, coef);
            coef = fmaf(A[c].y, w[c].y, coef);
            coef = fmaf(A[c].z, w[c].z, coef);
            coef = fmaf(A[c].w, w[c].w, coef);
        }
        int dl = (cur.x >> 24) & 31;
        atomicAdd(&acc[dl][lane], mg * coef);
        // advance pipeline
        idx = nidx;
        v0 = v1;
        cur = nxt;
        mg = mg2;
#pragma unroll
        for (int c = 0; c < 8; ++c) A[c] = B[c];
    }
    __syncthreads();
#pragma unroll
    for (int r = 0; r < 8; ++r) {
        int i = r * 256 + t;
        int n = b * 32 + (i >> 6);
        agg[(size_t)n * 64 + (i & 63)] = acc[i >> 6][i & 63];
    }
}

// ---------------- Kernel 5: GRU + epilogue ----------------
__global__ __launch_bounds__(256) void k_gru(const float* __restrict__ x,
                                             const float* __restrict__ agg,
                                             const float* __restrict__ Wih,
                                             const float* __restrict__ Whh,
                                             const float* __restrict__ bih,
                                             const float* __restrict__ bhh,
                                             float* __restrict__ out) {
    __shared__ float as_[64][64];
    __shared__ float xs[64][64];
    __shared__ float wi[16][193];
    __shared__ float wh[16][193];
    const int t = threadIdx.x;
    const int j = t & 63;
    const int g = t >> 6;
    const int base = blockIdx.x * 64;
#pragma unroll
    for (int r = 0; r < 16; ++r) {
        int idx = r * 256 + t;
        int n = idx >> 6, k = idx & 63;
        int gi = base + n;
        float av = 0.f, xv = 0.f;
        if (gi < NN) { av = agg[(size_t)gi * 64 + k]; xv = x[(size_t)gi * 64 + k]; }
        as_[n][k] = av;
        xs[n][k] = xv;
    }
    float ir[16], iz[16], inn[16], hr[16], hz[16], hn[16];
    float b0 = bih[j], b1 = bih[64 + j], b2 = bih[128 + j];
    float c0 = bhh[j], c1 = bhh[64 + j], c2 = bhh[128 + j];
#pragma unroll
    for (int q = 0; q < 16; ++q) {
        ir[q] = b0; iz[q] = b1; inn[q] = b2;
        hr[q] = c0; hz[q] = c1; hn[q] = c2;
    }
    for (int kc = 0; kc < 64; kc += 16) {
        __syncthreads();
#pragma unroll
        for (int r = 0; r < 12; ++r) {
            int idx = r * 256 + t;
            int row = idx >> 4, kk = idx & 15;
            wi[kk][row] = Wih[row * 64 + kc + kk];
            wh[kk][row] = Whh[row * 64 + kc + kk];
        }
        __syncthreads();
        for (int kk = 0; kk < 16; ++kk) {
            float wr = wi[kk][j], wz = wi[kk][64 + j], wn = wi[kk][128 + j];
            float vr = wh[kk][j], vz = wh[kk][64 + j], vn = wh[kk][128 + j];
#pragma unroll
            for (int q = 0; q < 16; ++q) {
                float a = as_[g * 16 + q][kc + kk];
                float xx = xs[g * 16 + q][kc + kk];
                ir[q] = fmaf(a, wr, ir[q]);
                iz[q] = fmaf(a, wz, iz[q]);
                inn[q] = fmaf(a, wn, inn[q]);
                hr[q] = fmaf(xx, vr, hr[q]);
                hz[q] = fmaf(xx, vz, hz[q]);
                hn[q] = fmaf(xx, vn, hn[q]);
            }
        }
    }
#pragma unroll
    for (int q = 0; q < 16; ++q) {
        int n = base + g * 16 + q;
        if (n < NN) {
            float r = 1.f / (1.f + __expf(-(ir[q] + hr[q])));
            float z = 1.f / (1.f + __expf(-(iz[q] + hz[q])));
            float nn = tanhf(inn[q] + r * hn[q]);
            float xv = xs[g * 16 + q][j];
            float h = (1.f - z) * nn + z * xv;
            float o = h > 0.f ? h : 0.f;
            out[(size_t)n * 64 + j] = 0.5f * o + 0.5f * xv;
        }
    }
}

extern "C" void kernel_launch(void* const* d_in, const int* in_sizes, int n_in,
                              void* d_out, int out_size, void* d_ws, size_t ws_size,
                              hipStream_t stream) {
    const float* x   = (const float*)d_in[0];
    const int*   ei  = (const int*)d_in[1];
    const float* ea  = (const float*)d_in[2];
    const float* We  = (const float*)d_in[3];
    const float* W   = (const float*)d_in[4];
    const float* Wih = (const float*)d_in[5];
    const float* Whh = (const float*)d_in[6];
    const float* bih = (const float*)d_in[7];
    const float* bhh = (const float*)d_in[8];
    float* out = (float*)d_out;

    // workspace layout
    char* ws = (char*)d_ws;
    float* m      = (float*)ws;                                   // 25.6 MB
    float* agg    = (float*)(ws + (size_t)NN * CC * 4);           // 25.6 MB
    int2*  sorted = (int2*)(ws + (size_t)2 * NN * CC * 4);        // 12.8 MB
    int*   counts = (int*)(ws + (size_t)2 * NN * CC * 4 + (size_t)NE * 8);
    int*   starts = counts + NB;                                  // NB+1 ints
    int*   cursor = starts + NB + 1;

    (void)in_sizes; (void)n_in; (void)out_size; (void)ws_size;

    int nb_nodes = (NN + 63) / 64;
    hipMemsetAsync(counts, 0, NB * sizeof(int), stream);
    k_xW<<<nb_nodes, 256, 0, stream>>>(x, W, m);
    k_hist<<<2048, 256, 0, stream>>>(ei, counts);
    k_scan<<<1, 256, 0, stream>>>(counts, starts, cursor);
    k_scatter<<<2048, 256, 0, stream>>>(ei, cursor, sorted);
    k_agg<<<NB, 256, 0, stream>>>(sorted, starts, ea, We, m, agg);
    k_gru<<<nb_nodes, 256, 0, stream>>>(x, agg, Wih, Whh, bih, bhh, out);
}

// Round 3
// 1041.687 us; speedup vs baseline: 1.0387x; 1.0387x over previous
//
#include <hip/hip_runtime.h>
#include <math.h>

#define NN 100000
#define NE 1600000
#define CC 64
#define ECH 32
#define NB 3125          // dst buckets of 32 nodes; 32*3125 == 100000 exactly

typedef unsigned int uint;
typedef unsigned short ushort;

__device__ __forceinline__ ushort f2bf1(float a) {
    uint u = __float_as_uint(a);
    u = (u + 0x7FFF + ((u >> 16) & 1)) >> 16;
    return (ushort)u;
}
__device__ __forceinline__ uint f2bf2(float a, float b) {
    return (uint)f2bf1(a) | ((uint)f2bf1(b) << 16);
}
__device__ __forceinline__ float bflo(uint v) { return __uint_as_float(v << 16); }
__device__ __forceinline__ float bfhi(uint v) { return __uint_as_float(v & 0xFFFF0000u); }

// ---------------- Kernel 1: m = x @ W  -> bf16 ----------------
__global__ __launch_bounds__(256) void k_xW(const float* __restrict__ x,
                                            const float* __restrict__ W,
                                            ushort* __restrict__ mbf) {
    __shared__ float xs[64][64];
    __shared__ float wsm[64][64];
    const int t = threadIdx.x;
    const int j = t & 63;
    const int g = t >> 6;
    const int base = blockIdx.x * 64;
#pragma unroll
    for (int r = 0; r < 16; ++r) {
        int idx = r * 256 + t;
        wsm[idx >> 6][idx & 63] = W[idx];
    }
#pragma unroll
    for (int r = 0; r < 16; ++r) {
        int idx = r * 256 + t;
        int n = idx >> 6, k = idx & 63;
        int gi = base + n;
        xs[n][k] = (gi < NN) ? x[(size_t)gi * 64 + k] : 0.f;
    }
    __syncthreads();
    float acc[16];
#pragma unroll
    for (int q = 0; q < 16; ++q) acc[q] = 0.f;
    for (int k = 0; k < 64; ++k) {
        float w = wsm[k][j];
#pragma unroll
        for (int q = 0; q < 16; ++q)
            acc[q] = fmaf(xs[g * 16 + q][k], w, acc[q]);
    }
#pragma unroll
    for (int q = 0; q < 16; ++q) {
        int n = base + g * 16 + q;
        if (n < NN) mbf[(size_t)n * 64 + j] = f2bf1(acc[q]);
    }
}

// ---------------- Pass 1: histogram of dst buckets ----------------
__global__ __launch_bounds__(256) void k_hist(const int* __restrict__ ei,
                                              int* __restrict__ counts) {
    int i = blockIdx.x * 256 + threadIdx.x;
    int stride = gridDim.x * 256;
    for (int e = i; e < NE; e += stride)
        atomicAdd(&counts[ei[NE + e] >> 5], 1);
}

// ---------------- Pass 2: exclusive scan (single block) ----------------
__global__ __launch_bounds__(256) void k_scan(const int* __restrict__ counts,
                                              int* __restrict__ starts,
                                              int* __restrict__ cursor) {
    __shared__ int part[256];
    __shared__ int lds[NB];
    const int t = threadIdx.x;
    const int per = (NB + 255) / 256;   // 13
    int base = t * per;
    int s = 0;
    for (int i = 0; i < per; ++i) {
        int g = base + i;
        int v = (g < NB) ? counts[g] : 0;
        if (g < NB) lds[g] = v;
        s += v;
    }
    part[t] = s;
    __syncthreads();
    for (int off = 1; off < 256; off <<= 1) {
        int v = (t >= off) ? part[t - off] : 0;
        __syncthreads();
        part[t] += v;
        __syncthreads();
    }
    int excl = (t == 0) ? 0 : part[t - 1];
    for (int i = 0; i < per; ++i) {
        int g = base + i;
        if (g < NB) {
            int v = lds[g];
            starts[g] = excl;
            cursor[g] = excl;
            excl += v;
        }
    }
    if (t == 255) starts[NB] = part[255];   // == NE
}

// ---------------- Pass 3: scatter bf16 ea rows + meta into bucket order ----
// meta: src (17 bits) | dst_local << 17 (5 bits)
__global__ __launch_bounds__(256) void k_scatter2(const int* __restrict__ ei,
                                                  const float* __restrict__ ea,
                                                  int* __restrict__ cursor,
                                                  const int* __restrict__ starts,
                                                  uint* __restrict__ sea,
                                                  uint* __restrict__ meta,
                                                  int bLo, int bHi, int cap) {
    const int base = starts[bLo];
    int i = blockIdx.x * 256 + threadIdx.x;
    int stride = gridDim.x * 256;
    for (int e = i; e < NE; e += stride) {
        int d = ei[NE + e];
        int bk = d >> 5;
        if (bk < bLo || bk >= bHi) continue;
        int s = ei[e];
        int pos = atomicAdd(&cursor[bk], 1) - base;
        if (pos < 0 || pos >= cap) continue;
        const float4* p = (const float4*)(ea + (size_t)e * 32);
        float4 v0 = p[0], v1 = p[1], v2 = p[2], v3 = p[3];
        float4 v4 = p[4], v5 = p[5], v6 = p[6], v7 = p[7];
        uint4 o0 = make_uint4(f2bf2(v0.x, v0.y), f2bf2(v0.z, v0.w),
                              f2bf2(v1.x, v1.y), f2bf2(v1.z, v1.w));
        uint4 o1 = make_uint4(f2bf2(v2.x, v2.y), f2bf2(v2.z, v2.w),
                              f2bf2(v3.x, v3.y), f2bf2(v3.z, v3.w));
        uint4 o2 = make_uint4(f2bf2(v4.x, v4.y), f2bf2(v4.z, v4.w),
                              f2bf2(v5.x, v5.y), f2bf2(v5.z, v5.w));
        uint4 o3 = make_uint4(f2bf2(v6.x, v6.y), f2bf2(v6.z, v6.w),
                              f2bf2(v7.x, v7.y), f2bf2(v7.z, v7.w));
        uint4* dst = (uint4*)(sea + (size_t)pos * 16);
        dst[0] = o0; dst[1] = o1; dst[2] = o2; dst[3] = o3;
        meta[pos] = (uint)s | ((uint)(d & 31) << 17);
    }
}

// ---------------- Pass 4: per-bucket LDS aggregation (streaming) -----------
__device__ __forceinline__ float edot(uint4 a0, uint4 a1, uint4 a2, uint4 a3,
                                      const float4 (&w)[8]) {
    float c = 0.f;
    c = fmaf(bflo(a0.x), w[0].x, c); c = fmaf(bfhi(a0.x), w[0].y, c);
    c = fmaf(bflo(a0.y), w[0].z, c); c = fmaf(bfhi(a0.y), w[0].w, c);
    c = fmaf(bflo(a0.z), w[1].x, c); c = fmaf(bfhi(a0.z), w[1].y, c);
    c = fmaf(bflo(a0.w), w[1].z, c); c = fmaf(bfhi(a0.w), w[1].w, c);
    c = fmaf(bflo(a1.x), w[2].x, c); c = fmaf(bfhi(a1.x), w[2].y, c);
    c = fmaf(bflo(a1.y), w[2].z, c); c = fmaf(bfhi(a1.y), w[2].w, c);
    c = fmaf(bflo(a1.z), w[3].x, c); c = fmaf(bfhi(a1.z), w[3].y, c);
    c = fmaf(bflo(a1.w), w[3].z, c); c = fmaf(bfhi(a1.w), w[3].w, c);
    c = fmaf(bflo(a2.x), w[4].x, c); c = fmaf(bfhi(a2.x), w[4].y, c);
    c = fmaf(bflo(a2.y), w[4].z, c); c = fmaf(bfhi(a2.y), w[4].w, c);
    c = fmaf(bflo(a2.z), w[5].x, c); c = fmaf(bfhi(a2.z), w[5].y, c);
    c = fmaf(bflo(a2.w), w[5].z, c); c = fmaf(bfhi(a2.w), w[5].w, c);
    c = fmaf(bflo(a3.x), w[6].x, c); c = fmaf(bfhi(a3.x), w[6].y, c);
    c = fmaf(bflo(a3.y), w[6].z, c); c = fmaf(bfhi(a3.y), w[6].w, c);
    c = fmaf(bflo(a3.z), w[7].x, c); c = fmaf(bfhi(a3.z), w[7].y, c);
    c = fmaf(bflo(a3.w), w[7].z, c); c = fmaf(bfhi(a3.w), w[7].w, c);
    return c;
}

__global__ __launch_bounds__(512) void k_agg(const uint* __restrict__ sea,
                                             const uint* __restrict__ meta,
                                             const int* __restrict__ starts,
                                             const ushort* __restrict__ mbf,
                                             const float* __restrict__ We,
                                             float* __restrict__ agg, int bLo) {
    __shared__ float acc[32][64];
    const int t = threadIdx.x;
    const int lane = t & 63;
    const int wv = t >> 6;            // 0..7
    const int b = bLo + blockIdx.x;
    const int base = starts[bLo];
#pragma unroll
    for (int r = 0; r < 4; ++r) {
        int i2 = r * 512 + t;
        acc[i2 >> 6][i2 & 63] = 0.f;
    }
    float4 w[8];
    {
        const float4* wp = (const float4*)(We + lane * 32);
#pragma unroll
        for (int c = 0; c < 8; ++c) w[c] = wp[c];
    }
    __syncthreads();
    const int lo = starts[b] - base;
    const int cnt = starts[b + 1] - base - lo;
    const int len = (cnt + 7) >> 3;
    const int mylo = lo + wv * len;
    int n = cnt - wv * len;
    n = (n < 0) ? 0 : ((n > len) ? len : n);

    const uint4* s4 = (const uint4*)sea;
    uint4 Z = make_uint4(0, 0, 0, 0);
    uint4 A0 = Z, A1 = Z, A2 = Z, A3 = Z, B0 = Z, B1 = Z, B2 = Z, B3 = Z;
    float mA = 0.f, mB = 0.f;
    uint meA = 0, meB = 0, meC = 0, meD = 0;
    if (n > 0) meA = meta[mylo];
    if (n > 1) meB = meta[mylo + 1];
    if (n > 2) meC = meta[mylo + 2];
    if (n > 3) meD = meta[mylo + 3];
    if (n > 0) {
        size_t r = (size_t)mylo * 4;
        A0 = s4[r]; A1 = s4[r + 1]; A2 = s4[r + 2]; A3 = s4[r + 3];
        mA = __uint_as_float((uint)mbf[(size_t)(meA & 0x1FFFF) * 64 + lane] << 16);
    }
    if (n > 1) {
        size_t r = (size_t)(mylo + 1) * 4;
        B0 = s4[r]; B1 = s4[r + 1]; B2 = s4[r + 2]; B3 = s4[r + 3];
        mB = __uint_as_float((uint)mbf[(size_t)(meB & 0x1FFFF) * 64 + lane] << 16);
    }
    int k = 0;
    while (k < n) {
        uint meE = (k + 4 < n) ? meta[mylo + k + 4] : 0;
        uint4 N0 = Z, N1 = Z, N2 = Z, N3 = Z;
        float mN = 0.f;
        if (k + 2 < n) {
            size_t r = (size_t)(mylo + k + 2) * 4;
            N0 = s4[r]; N1 = s4[r + 1]; N2 = s4[r + 2]; N3 = s4[r + 3];
            mN = __uint_as_float((uint)mbf[(size_t)(meC & 0x1FFFF) * 64 + lane] << 16);
        }
        {   // edge k
            float coef = edot(A0, A1, A2, A3, w);
            atomicAdd(&acc[(meA >> 17) & 31][lane], mA * coef);
        }
        uint meF = (k + 5 < n) ? meta[mylo + k + 5] : 0;
        uint4 P0 = Z, P1 = Z, P2 = Z, P3 = Z;
        float mP = 0.f;
        if (k + 3 < n) {
            size_t r = (size_t)(mylo + k + 3) * 4;
            P0 = s4[r]; P1 = s4[r + 1]; P2 = s4[r + 2]; P3 = s4[r + 3];
            mP = __uint_as_float((uint)mbf[(size_t)(meD & 0x1FFFF) * 64 + lane] << 16);
        }
        if (k + 1 < n) {   // edge k+1
            float coef = edot(B0, B1, B2, B3, w);
            atomicAdd(&acc[(meB >> 17) & 31][lane], mB * coef);
        }
        A0 = N0; A1 = N1; A2 = N2; A3 = N3; mA = mN; meA = meC;
        B0 = P0; B1 = P1; B2 = P2; B3 = P3; mB = mP; meB = meD;
        meC = meE; meD = meF;
        k += 2;
    }
    __syncthreads();
#pragma unroll
    for (int r = 0; r < 4; ++r) {
        int i2 = r * 512 + t;
        int nrow = b * 32 + (i2 >> 6);
        agg[(size_t)nrow * 64 + (i2 & 63)] = acc[i2 >> 6][i2 & 63];
    }
}

// ---------------- Kernel 5: GRU + epilogue (in-place on agg buffer) --------
__global__ __launch_bounds__(256) void k_gru(const float* __restrict__ x,
                                             const float* agg,
                                             const float* __restrict__ Wih,
                                             const float* __restrict__ Whh,
                                             const float* __restrict__ bih,
                                             const float* __restrict__ bhh,
                                             float* out) {
    __shared__ float as_[64][64];
    __shared__ float xs[64][64];
    __shared__ float wi[16][193];
    __shared__ float wh[16][193];
    const int t = threadIdx.x;
    const int j = t & 63;
    const int g = t >> 6;
    const int base = blockIdx.x * 64;
#pragma unroll
    for (int r = 0; r < 16; ++r) {
        int idx = r * 256 + t;
        int n = idx >> 6, k = idx & 63;
        int gi = base + n;
        float av = 0.f, xv = 0.f;
        if (gi < NN) { av = agg[(size_t)gi * 64 + k]; xv = x[(size_t)gi * 64 + k]; }
        as_[n][k] = av;
        xs[n][k] = xv;
    }
    float ir[16], iz[16], inn[16], hr[16], hz[16], hn[16];
    float b0 = bih[j], b1 = bih[64 + j], b2 = bih[128 + j];
    float c0 = bhh[j], c1 = bhh[64 + j], c2 = bhh[128 + j];
#pragma unroll
    for (int q = 0; q < 16; ++q) {
        ir[q] = b0; iz[q] = b1; inn[q] = b2;
        hr[q] = c0; hz[q] = c1; hn[q] = c2;
    }
    for (int kc = 0; kc < 64; kc += 16) {
        __syncthreads();
#pragma unroll
        for (int r = 0; r < 12; ++r) {
            int idx = r * 256 + t;
            int row = idx >> 4, kk = idx & 15;
            wi[kk][row] = Wih[row * 64 + kc + kk];
            wh[kk][row] = Whh[row * 64 + kc + kk];
        }
        __syncthreads();
        for (int kk = 0; kk < 16; ++kk) {
            float wr = wi[kk][j], wz = wi[kk][64 + j], wn = wi[kk][128 + j];
            float vr = wh[kk][j], vz = wh[kk][64 + j], vn = wh[kk][128 + j];
#pragma unroll
            for (int q = 0; q < 16; ++q) {
                float a = as_[g * 16 + q][kc + kk];
                float xx = xs[g * 16 + q][kc + kk];
                ir[q] = fmaf(a, wr, ir[q]);
                iz[q] = fmaf(a, wz, iz[q]);
                inn[q] = fmaf(a, wn, inn[q]);
                hr[q] = fmaf(xx, vr, hr[q]);
                hz[q] = fmaf(xx, vz, hz[q]);
                hn[q] = fmaf(xx, vn, hn[q]);
            }
        }
    }
    __syncthreads();
#pragma unroll
    for (int q = 0; q < 16; ++q) {
        int n = base + g * 16 + q;
        if (n < NN) {
            float r = 1.f / (1.f + __expf(-(ir[q] + hr[q])));
            float z = 1.f / (1.f + __expf(-(iz[q] + hz[q])));
            float nn = tanhf(inn[q] + r * hn[q]);
            float xv = xs[g * 16 + q][j];
            float h = (1.f - z) * nn + z * xv;
            float o = h > 0.f ? h : 0.f;
            out[(size_t)n * 64 + j] = 0.5f * o + 0.5f * xv;
        }
    }
}

extern "C" void kernel_launch(void* const* d_in, const int* in_sizes, int n_in,
                              void* d_out, int out_size, void* d_ws, size_t ws_size,
                              hipStream_t stream) {
    const float* x   = (const float*)d_in[0];
    const int*   ei  = (const int*)d_in[1];
    const float* ea  = (const float*)d_in[2];
    const float* We  = (const float*)d_in[3];
    const float* W   = (const float*)d_in[4];
    const float* Wih = (const float*)d_in[5];
    const float* Whh = (const float*)d_in[6];
    const float* bih = (const float*)d_in[7];
    const float* bhh = (const float*)d_in[8];
    float* out = (float*)d_out;
    float* agg = (float*)d_out;    // agg lives in d_out; k_gru rewrites in-place

    char* ws = (char*)d_ws;
    ushort* mbf = (ushort*)ws;
    size_t off = ((size_t)NN * CC * 2 + 255) & ~(size_t)255;
    int* counts = (int*)(ws + off); off += (size_t)NB * 4;
    int* starts = (int*)(ws + off); off += (size_t)(NB + 1) * 4;
    int* cursor = (int*)(ws + off); off += (size_t)NB * 4;
    off = (off + 255) & ~(size_t)255;

    // choose pass count so (sea + meta) fits in remaining workspace
    int P = 8, cap = NE / 8 + NE / 8;
    for (int trial = 1; trial <= 8; trial <<= 1) {
        int c = (trial == 1) ? NE : (NE / trial + NE / 8);
        size_t need = off + (size_t)c * 64 + (size_t)c * 4 + 512;
        if (need <= ws_size) { P = trial; cap = c; break; }
    }
    uint* sea  = (uint*)(ws + off); off += (size_t)cap * 64;
    uint* meta = (uint*)(ws + off);

    (void)in_sizes; (void)n_in; (void)out_size;

    int nb_nodes = (NN + 63) / 64;
    k_xW<<<nb_nodes, 256, 0, stream>>>(x, W, mbf);
    hipMemsetAsync(counts, 0, NB * sizeof(int), stream);
    k_hist<<<1024, 256, 0, stream>>>(ei, counts);
    k_scan<<<1, 256, 0, stream>>>(counts, starts, cursor);
    int NBP = (NB + P - 1) / P;
    for (int p = 0; p < P; ++p) {
        int bLo = p * NBP;
        int bHi = (NB < (p + 1) * NBP) ? NB : (p + 1) * NBP;
        if (bLo >= bHi) break;
        k_scatter2<<<2048, 256, 0, stream>>>(ei, ea, cursor, starts, sea, meta, bLo, bHi, cap);
        k_agg<<<bHi - bLo, 512, 0, stream>>>(sea, meta, starts, mbf, We, agg, bLo);
    }
    k_gru<<<nb_nodes, 256, 0, stream>>>(x, agg, Wih, Whh, bih, bhh, out);
}